// Round 1
// baseline (708.370 us; speedup 1.0000x reference)
//
#include <hip/hip_runtime.h>
#include <math.h>

#define BB 4
#define NN 4096

// workspace layout (float offsets)
#define OFF_L1META 0        // 64 x 8: {w0[c][0..3], b0f[c], pad3}
#define OFF_W1T    512      // W1T[c][o] = w1[o][c]*s1[o]  (4096)
#define OFF_B1     4608     // 64
#define OFF_W2     4672     // W2f[o][c] row-major (8192)
#define OFF_B2     12864    // 128
#define OFF_PACK   12992    // float4 refs: [set][b][j] = (x,y,z,|r|^2)  (131072 floats)
#define OFF_IDX    144064   // int knn idx: [b][n][32]  (524288 ints)

__device__ __forceinline__ void insert16(float (&bd)[16], int (&bi)[16], float t, int ti) {
#pragma unroll
  for (int i = 0; i < 16; ++i) {
    bool sw = t < bd[i];
    float od = bd[i]; int oi = bi[i];
    bd[i] = sw ? t : od;  bi[i] = sw ? ti : oi;
    t     = sw ? od : t;  ti    = sw ? oi : ti;
  }
}

__global__ __launch_bounds__(256) void prep_kernel(
    const float* __restrict__ p1, const float* __restrict__ p2,
    const float* __restrict__ w0, const float* __restrict__ b0, const float* __restrict__ g0,
    const float* __restrict__ be0, const float* __restrict__ m0, const float* __restrict__ v0,
    const float* __restrict__ w1, const float* __restrict__ b1, const float* __restrict__ g1,
    const float* __restrict__ be1, const float* __restrict__ m1, const float* __restrict__ v1,
    const float* __restrict__ w2, const float* __restrict__ b2, const float* __restrict__ g2,
    const float* __restrict__ be2, const float* __restrict__ m2, const float* __restrict__ v2,
    float* __restrict__ ws) {
  int gid = blockIdx.x * 256 + threadIdx.x;
  // pack reference points with |r|^2
  if (gid < 2 * BB * NN) {
    int set = gid >> 14;
    int rem = gid & (BB * NN - 1);
    int b = rem >> 12, j = rem & (NN - 1);
    const float* p = set ? p2 : p1;
    float x = p[(b * 3 + 0) * NN + j];
    float y = p[(b * 3 + 1) * NN + j];
    float z = p[(b * 3 + 2) * NN + j];
    ((float4*)(ws + OFF_PACK))[gid] = make_float4(x, y, z, x * x + y * y + z * z);
  }
  // fused BN weights
  if (gid < 512) {                         // L1meta [c][8]
    int c = gid >> 3, f = gid & 7;
    float s = g0[c] / sqrtf(v0[c] + 1e-3f);
    float val = 0.f;
    if (f < 4)       val = w0[c * 4 + f] * s;
    else if (f == 4) val = (b0[c] - m0[c]) * s + be0[c];
    ws[OFF_L1META + gid] = val;
  } else if (gid < 4608) {                 // W1T[c][o]
    int wg = gid - 512;
    int c = wg >> 6, o = wg & 63;
    float s = g1[o] / sqrtf(v1[o] + 1e-3f);
    ws[OFF_W1T + wg] = w1[o * 64 + c] * s;
  } else if (gid < 4672) {                 // B1
    int o = gid - 4608;
    float s = g1[o] / sqrtf(v1[o] + 1e-3f);
    ws[OFF_B1 + o] = (b1[o] - m1[o]) * s + be1[o];
  } else if (gid < 12864) {                // W2[o][c]
    int wg = gid - 4672;
    int o = wg >> 6;
    float s = g2[o] / sqrtf(v2[o] + 1e-3f);
    ws[OFF_W2 + wg] = w2[wg] * s;
  } else if (gid < 12992) {                // B2
    int o = gid - 12864;
    float s = g2[o] / sqrtf(v2[o] + 1e-3f);
    ws[OFF_B2 + o] = (b2[o] - m2[o]) * s + be2[o];
  }
}

// grid: B * (N/64 chunks) * 2 sets = 512 blocks; block: 256 = 4 waves (ref-splits) x 64 queries
__global__ __launch_bounds__(256) void knn_kernel(const float* __restrict__ p1,
                                                  float* __restrict__ ws) {
  const int tid = threadIdx.x;
  const int lane = tid & 63;
  const int split = __builtin_amdgcn_readfirstlane(tid >> 6);  // wave-uniform 0..3
  const int set = blockIdx.x & 1;
  const int chunk = (blockIdx.x >> 1) & 63;
  const int b = blockIdx.x >> 7;
  const int n = (chunk << 6) | lane;

  const float qx = p1[(b * 3 + 0) * NN + n];
  const float qy = p1[(b * 3 + 1) * NN + n];
  const float qz = p1[(b * 3 + 2) * NN + n];
  const float qq = qx * qx + qy * qy + qz * qz;

  const float4* __restrict__ pk =
      ((const float4*)(ws + OFF_PACK)) + (size_t)(set * BB + b) * NN;

  float bd[16]; int bi[16];
#pragma unroll
  for (int i = 0; i < 16; ++i) { bd[i] = INFINITY; bi[i] = 0; }
  float worst = INFINITY;

  const int j0 = split << 10;
  for (int jb = j0; jb < j0 + 1024; jb += 4) {
    float d[4];
#pragma unroll
    for (int r = 0; r < 4; ++r) {
      float4 rv = pk[jb + r];
      float dt = qx * rv.x + qy * rv.y + qz * rv.z;
      d[r] = (qq - 2.f * dt) + rv.w;   // same formula as reference d2
    }
    // min-of-4 pre-filter (strict < keeps earliest index on ties)
    float m = d[0]; int mi = 0;
    if (d[1] < m) { m = d[1]; mi = 1; }
    if (d[2] < m) { m = d[2]; mi = 2; }
    if (d[3] < m) { m = d[3]; mi = 3; }
    if (m < worst) {
      insert16(bd, bi, m, jb + mi);
      worst = bd[15];
#pragma unroll
      for (int r = 0; r < 4; ++r) {
        if (d[r] < worst && r != mi) {   // rare second inserts
          insert16(bd, bi, d[r], jb + r);
          worst = bd[15];
        }
      }
    }
  }

  __shared__ float sd[256 * 16];
  __shared__ int   si[256 * 16];
#pragma unroll
  for (int i = 0; i < 16; ++i) { sd[tid * 16 + i] = bd[i]; si[tid * 16 + i] = bi[i]; }
  __syncthreads();

  if (tid < 64) {
    float md[16]; int mj[16];
#pragma unroll
    for (int i = 0; i < 16; ++i) { md[i] = sd[tid * 16 + i]; mj[i] = si[tid * 16 + i]; }
#pragma unroll 1
    for (int s = 1; s < 4; ++s) {
      int base = ((s << 6) | tid) << 4;
#pragma unroll 1
      for (int i = 0; i < 16; ++i) {
        float t = sd[base + i];
        if (t < md[15]) insert16(md, mj, t, si[base + i]);
      }
    }
    int* knn_idx = (int*)(ws + OFF_IDX);
    int ob = (((b << 12) | n) << 5) + (set << 4);
#pragma unroll
    for (int i = 0; i < 16; ++i) knn_idx[ob + i] = mj[i];
  }
}

// grid: 524288/256 = 2048 blocks; thread = (b, n, kk); wave = 2 queries x 32 kk
__global__ __launch_bounds__(256) void fusion_kernel(const float* __restrict__ p1,
                                                     const float* __restrict__ ws,
                                                     float* __restrict__ out) {
  const int pos = blockIdx.x * 256 + threadIdx.x;
  const int kk = pos & 31;
  const int n = (pos >> 5) & (NN - 1);
  const int b = pos >> 17;

  const float qx = p1[(b * 3 + 0) * NN + n];
  const float qy = p1[(b * 3 + 1) * NN + n];
  const float qz = p1[(b * 3 + 2) * NN + n];

  const int set = kk >> 4;
  const int* knn_idx = (const int*)(ws + OFF_IDX);
  const int id = knn_idx[((((b << 12) | n)) << 5) | kk];
  const float4 rv = ((const float4*)(ws + OFF_PACK))[(set * BB + b) * NN + id];

  const float rx = rv.x - qx, ry = rv.y - qy, rz = rv.z - qz;
  const float sq = rx * rx + ry * ry + rz * rz;
  const float dist = sqrtf(fmaxf(sq, 1e-12f));

  // layers 0+1: dynamic c-loop, h0[c] recomputed (4 FMAs); h1[o] constant-indexed
  float h1[64];
#pragma unroll
  for (int o = 0; o < 64; ++o) h1[o] = 0.f;
#pragma unroll 1
  for (int c = 0; c < 64; ++c) {
    const float* mr = ws + OFF_L1META + c * 8;
    float h0 = mr[4] + mr[0] * rx + mr[1] * ry + mr[2] * rz + mr[3] * dist;
    h0 = fmaxf(h0, 0.f);
    const float* wr = ws + OFF_W1T + c * 64;
#pragma unroll
    for (int o = 0; o < 64; ++o) h1[o] = fmaf(wr[o], h0, h1[o]);
  }
#pragma unroll
  for (int o = 0; o < 64; ++o) h1[o] = fmaxf(h1[o] + ws[OFF_B1 + o], 0.f);

  // layer 2: only the channel max is needed
  float mx = -INFINITY;
#pragma unroll 1
  for (int o = 0; o < 128; ++o) {
    const float* wr = ws + OFF_W2 + o * 64;
    float acc = ws[OFF_B2 + o];
#pragma unroll
    for (int c = 0; c < 64; ++c) acc = fmaf(wr[c], h1[c], acc);
    mx = fmaxf(mx, acc);
  }
  mx = fmaxf(mx, 0.f);  // relu commutes with channel-max

  // softmax over the 32 kk lanes + weighted sum of neighbor coords
  float gm = mx;
#pragma unroll
  for (int off = 16; off > 0; off >>= 1) gm = fmaxf(gm, __shfl_xor(gm, off));
  float e = __expf(mx - gm);
  float es = e, ex = e * rv.x, ey = e * rv.y, ez = e * rv.z;
#pragma unroll
  for (int off = 16; off > 0; off >>= 1) {
    es += __shfl_xor(es, off);
    ex += __shfl_xor(ex, off);
    ey += __shfl_xor(ey, off);
    ez += __shfl_xor(ez, off);
  }
  if (kk == 0) {
    float inv = 1.f / es;
    out[(b * 3 + 0) * NN + n] = ex * inv;
    out[(b * 3 + 1) * NN + n] = ey * inv;
    out[(b * 3 + 2) * NN + n] = ez * inv;
  }
}

extern "C" void kernel_launch(void* const* d_in, const int* in_sizes, int n_in,
                              void* d_out, int out_size, void* d_ws, size_t ws_size,
                              hipStream_t stream) {
  const float* p1 = (const float*)d_in[0];
  const float* p2 = (const float*)d_in[1];
  // d_in[2] = k (fixed 16)
  float* ws = (float*)d_ws;
  float* out = (float*)d_out;

  prep_kernel<<<128, 256, 0, stream>>>(
      p1, p2,
      (const float*)d_in[3],  (const float*)d_in[4],  (const float*)d_in[5],
      (const float*)d_in[6],  (const float*)d_in[7],  (const float*)d_in[8],
      (const float*)d_in[9],  (const float*)d_in[10], (const float*)d_in[11],
      (const float*)d_in[12], (const float*)d_in[13], (const float*)d_in[14],
      (const float*)d_in[15], (const float*)d_in[16], (const float*)d_in[17],
      (const float*)d_in[18], (const float*)d_in[19], (const float*)d_in[20],
      ws);
  knn_kernel<<<512, 256, 0, stream>>>(p1, ws);
  fusion_kernel<<<2048, 256, 0, stream>>>(p1, ws, out);
}

// Round 2
// 487.321 us; speedup vs baseline: 1.4536x; 1.4536x over previous
//
#include <hip/hip_runtime.h>
#include <math.h>

#define BB 4
#define NN 4096

// workspace layout (float offsets)
#define OFF_W0S   0        // 256: w0*s0 [c][4]
#define OFF_B0F   256      // 64: fused bias0
#define OFF_W1T   320      // 4096: W1T[c][o] = w1[o][c]*s1[o]
#define OFF_B1    4416     // 64
#define OFF_W2    4480     // 8192: W2[o][c]*s2[o]
#define OFF_B2    12672    // 128
#define OFF_PACK  12800    // float4 refs [set][b][j] = (x,y,z,|r|^2)  (131072 floats)
#define OFF_IDX   143872   // int knn idx [b][n][32] (524288 ints)

typedef float v2f __attribute__((ext_vector_type(2)));

static __device__ __forceinline__ v2f vfma2(v2f a, v2f b, v2f c) {
#if __has_builtin(__builtin_elementwise_fma)
  return __builtin_elementwise_fma(a, b, c);
#else
  v2f r; r.x = fmaf(a.x, b.x, c.x); r.y = fmaf(a.y, b.y, c.y); return r;
#endif
}
static __device__ __forceinline__ v2f vmax2(v2f a, v2f b) {
#if __has_builtin(__builtin_elementwise_max)
  return __builtin_elementwise_max(a, b);
#else
  v2f r; r.x = fmaxf(a.x, b.x); r.y = fmaxf(a.y, b.y); return r;
#endif
}
static __device__ __forceinline__ v2f mkv2(float a, float b) {
  v2f r; r.x = a; r.y = b; return r;
}

__global__ __launch_bounds__(256) void prep_kernel(
    const float* __restrict__ p1, const float* __restrict__ p2,
    const float* __restrict__ w0, const float* __restrict__ b0, const float* __restrict__ g0,
    const float* __restrict__ be0, const float* __restrict__ m0, const float* __restrict__ v0,
    const float* __restrict__ w1, const float* __restrict__ b1, const float* __restrict__ g1,
    const float* __restrict__ be1, const float* __restrict__ m1, const float* __restrict__ v1,
    const float* __restrict__ w2, const float* __restrict__ b2, const float* __restrict__ g2,
    const float* __restrict__ be2, const float* __restrict__ m2, const float* __restrict__ v2,
    float* __restrict__ ws) {
  int gid = blockIdx.x * 256 + threadIdx.x;
  // pack reference points with |r|^2 (one float4 per gid, 32768 total)
  if (gid < 2 * BB * NN) {
    int set = gid >> 14;
    int rem = gid & (BB * NN - 1);
    int b = rem >> 12, j = rem & (NN - 1);
    const float* p = set ? p2 : p1;
    float x = p[(b * 3 + 0) * NN + j];
    float y = p[(b * 3 + 1) * NN + j];
    float z = p[(b * 3 + 2) * NN + j];
    ((float4*)(ws + OFF_PACK))[gid] = make_float4(x, y, z, x * x + y * y + z * z);
  }
  // fused BN weights
  if (gid < 256) {                         // W0S[c][4]
    int c = gid >> 2, f = gid & 3;
    float s = g0[c] / sqrtf(v0[c] + 1e-3f);
    ws[OFF_W0S + gid] = w0[c * 4 + f] * s;
  } else if (gid < 320) {                  // B0F
    int c = gid - 256;
    float s = g0[c] / sqrtf(v0[c] + 1e-3f);
    ws[OFF_B0F + c] = (b0[c] - m0[c]) * s + be0[c];
  } else if (gid < 4416) {                 // W1T[c][o]
    int wg = gid - 320;
    int c = wg >> 6, o = wg & 63;
    float s = g1[o] / sqrtf(v1[o] + 1e-3f);
    ws[OFF_W1T + wg] = w1[o * 64 + c] * s;
  } else if (gid < 4480) {                 // B1
    int o = gid - 4416;
    float s = g1[o] / sqrtf(v1[o] + 1e-3f);
    ws[OFF_B1 + o] = (b1[o] - m1[o]) * s + be1[o];
  } else if (gid < 12672) {                // W2[o][c]
    int wg = gid - 4480;
    int o = wg >> 6;
    float s = g2[o] / sqrtf(v2[o] + 1e-3f);
    ws[OFF_W2 + wg] = w2[wg] * s;
  } else if (gid < 12800) {                // B2
    int o = gid - 12672;
    float s = g2[o] / sqrtf(v2[o] + 1e-3f);
    ws[OFF_B2 + o] = (b2[o] - m2[o]) * s + be2[o];
  }
}

// grid: B * (N/64) * 2 sets = 512 blocks; block: 256 = 4 ref-splits x 64 queries
// Two-pass exact selection: pass1 = top-16 distances (uint keys, 2-instr/step insert),
// merge -> exact 16th-smallest threshold; pass2 = branchless candidate push; final
// exact (d,idx) select with reference tie-break (idx ascending).
__global__ __launch_bounds__(256) void knn_kernel(const float* __restrict__ p1,
                                                  const float4* __restrict__ pkall,
                                                  int* __restrict__ idx_out) {
  const int tid = threadIdx.x;
  const int lane = tid & 63;
  const int wv = __builtin_amdgcn_readfirstlane(tid >> 6);  // ref split 0..3
  const int set = blockIdx.x & 1;
  const int chunk = (blockIdx.x >> 1) & 63;
  const int b = blockIdx.x >> 7;
  const int n = (chunk << 6) | lane;

  const float qx = p1[(b * 3 + 0) * NN + n];
  const float qy = p1[(b * 3 + 1) * NN + n];
  const float qz = p1[(b * 3 + 2) * NN + n];
  const float qq = qx * qx + qy * qy + qz * qz;

  const float4* __restrict__ pk = pkall + (size_t)(set * BB + b) * NN;

  // ---- pass 1: per-lane top-16 distance keys over this split ----
  unsigned bk[16];
#pragma unroll
  for (int i = 0; i < 16; ++i) bk[i] = 0xFFFFFFFFu;
  unsigned worst = 0xFFFFFFFFu;

  const int j0 = wv << 10;
  for (int jb = j0; jb < j0 + 1024; jb += 4) {
    unsigned kq[4];
#pragma unroll
    for (int r = 0; r < 4; ++r) {
      float4 rv = pk[jb + r];
      float dt = qx * rv.x + qy * rv.y + qz * rv.z;
      float d = fmaxf((qq - 2.f * dt) + rv.w, 0.f);
      kq[r] = __float_as_uint(d);
    }
    unsigned m = kq[0]; int mi = 0;
    if (kq[1] < m) { m = kq[1]; mi = 1; }
    if (kq[2] < m) { m = kq[2]; mi = 2; }
    if (kq[3] < m) { m = kq[3]; mi = 3; }
    if (m < worst) {
      unsigned t = m;
#pragma unroll
      for (int i = 0; i < 16; ++i) { unsigned lo = min(t, bk[i]); t = max(t, bk[i]); bk[i] = lo; }
      worst = bk[15];
#pragma unroll
      for (int r = 0; r < 4; ++r) {
        if (r != mi && kq[r] < worst) {
          unsigned t2 = kq[r];
#pragma unroll
          for (int i = 0; i < 16; ++i) { unsigned lo = min(t2, bk[i]); t2 = max(t2, bk[i]); bk[i] = lo; }
          worst = bk[15];
        }
      }
    }
  }

  __shared__ unsigned skeys[256 * 17];   // stride 17: conflict-free write/read
  __shared__ unsigned sthr[64];
#pragma unroll
  for (int i = 0; i < 16; ++i) skeys[tid * 17 + i] = bk[i];
  __syncthreads();

  // ---- merge 4 sorted lists -> exact global 16th-smallest ----
  if (tid < 64) {
    unsigned md[16];
#pragma unroll
    for (int i = 0; i < 16; ++i) md[i] = skeys[tid * 17 + i];
#pragma unroll 1
    for (int s = 1; s < 4; ++s) {
      int base = ((s << 6) | tid) * 17;
#pragma unroll 1
      for (int i = 0; i < 16; ++i) {
        unsigned t = skeys[base + i];
        if (t >= md[15]) break;   // list is sorted: rest can't qualify
#pragma unroll
        for (int j = 0; j < 16; ++j) { unsigned lo = min(t, md[j]); t = max(t, md[j]); md[j] = lo; }
      }
    }
    sthr[tid] = md[15];
  }
  __syncthreads();

  // ---- pass 2: collect candidates <= threshold (+256 ulp guard) ----
  __shared__ unsigned cand_d[256 * 16];
  __shared__ int cand_i[256 * 16];
  __shared__ int ccnt[256];
  const unsigned thrL = sthr[lane] + 256u;
  int cnt = 0;
  const int cslot = (lane << 2) | wv;
  const int cbase = cslot << 4;
  for (int jb = j0; jb < j0 + 1024; jb += 4) {
    unsigned kq[4];
#pragma unroll
    for (int r = 0; r < 4; ++r) {
      float4 rv = pk[jb + r];
      float dt = qx * rv.x + qy * rv.y + qz * rv.z;
      float d = fmaxf((qq - 2.f * dt) + rv.w, 0.f);
      kq[r] = __float_as_uint(d);
    }
#pragma unroll
    for (int r = 0; r < 4; ++r) {
      if (kq[r] <= thrL && cnt < 16) {
        cand_d[cbase + cnt] = kq[r];
        cand_i[cbase + cnt] = jb + r;
        ++cnt;
      }
    }
  }
  ccnt[cslot] = cnt;
  __syncthreads();

  // ---- final: exact select 16 smallest (ties -> lower idx) ----
  if (tid < 64) {
    unsigned md[16]; int mi[16];
#pragma unroll
    for (int i = 0; i < 16; ++i) { md[i] = 0xFFFFFFFFu; mi[i] = 0; }
#pragma unroll 1
    for (int s = 0; s < 4; ++s) {
      int slot = (tid << 2) | s;
      int cn = ccnt[slot];
#pragma unroll 1
      for (int i = 0; i < cn; ++i) {
        unsigned t = cand_d[(slot << 4) + i];
        int ti = cand_i[(slot << 4) + i];
        if (t < md[15]) {
#pragma unroll
          for (int j = 0; j < 16; ++j) {
            bool sw = t < md[j];
            unsigned od = md[j]; int oi = mi[j];
            md[j] = sw ? t : od;  mi[j] = sw ? ti : oi;
            t = sw ? od : t;      ti = sw ? oi : ti;
          }
        }
      }
    }
    int nq = (chunk << 6) | tid;
    int ob = (((b << 12) | nq) << 5) + (set << 4);
#pragma unroll
    for (int i = 0; i < 16; ++i) idx_out[ob + i] = mi[i];
  }
}

// grid: 2048 blocks x 256; thread = (b, n, kk); packed-fp32 (v_pk_fma_f32) MLP
__global__ __launch_bounds__(256) void fusion_kernel(const float* __restrict__ p1,
                                                     const float* __restrict__ wts,
                                                     const float4* __restrict__ pkall,
                                                     const int* __restrict__ knn_idx,
                                                     float* __restrict__ out) {
  const int pos = blockIdx.x * 256 + threadIdx.x;
  const int kk = pos & 31;
  const int n = (pos >> 5) & (NN - 1);
  const int b = pos >> 17;

  const float qx = p1[(b * 3 + 0) * NN + n];
  const float qy = p1[(b * 3 + 1) * NN + n];
  const float qz = p1[(b * 3 + 2) * NN + n];

  const int set = kk >> 4;
  const int id = knn_idx[(((b << 12) | n) << 5) | kk];
  const float4 rv = pkall[(size_t)(set * BB + b) * NN + id];

  const float rx = rv.x - qx, ry = rv.y - qy, rz = rv.z - qz;
  const float sq = rx * rx + ry * ry + rz * rz;
  const float dist = sqrtf(fmaxf(sq, 1e-12f));

  // layers 0+1: h0[c] recomputed per c (4 FMAs); h1 packed as 32 x float2
  v2f h1v[32];
#pragma unroll
  for (int j = 0; j < 32; ++j) h1v[j] = mkv2(0.f, 0.f);

#pragma unroll 2
  for (int c = 0; c < 64; ++c) {
    float4 m = ((const float4*)(wts + OFF_W0S))[c];
    float h0 = fmaf(m.x, rx, fmaf(m.y, ry, fmaf(m.z, rz, fmaf(m.w, dist, wts[OFF_B0F + c]))));
    h0 = fmaxf(h0, 0.f);
    v2f h0v = mkv2(h0, h0);
    const float4* w4 = (const float4*)(wts + OFF_W1T + (c << 6));
#pragma unroll
    for (int q = 0; q < 16; ++q) {
      float4 w = w4[q];
      h1v[2 * q]     = vfma2(mkv2(w.x, w.y), h0v, h1v[2 * q]);
      h1v[2 * q + 1] = vfma2(mkv2(w.z, w.w), h0v, h1v[2 * q + 1]);
    }
  }
  {
    const float4* b14 = (const float4*)(wts + OFF_B1);
#pragma unroll
    for (int q = 0; q < 16; ++q) {
      float4 bb = b14[q];
      h1v[2 * q]     = vmax2(h1v[2 * q] + mkv2(bb.x, bb.y), mkv2(0.f, 0.f));
      h1v[2 * q + 1] = vmax2(h1v[2 * q + 1] + mkv2(bb.z, bb.w), mkv2(0.f, 0.f));
    }
  }

  // layer 2: only channel max needed; 2 packed acc chains per o
  float mx = -INFINITY;
#pragma unroll 2
  for (int o = 0; o < 128; ++o) {
    const float4* w4 = (const float4*)(wts + OFF_W2 + (o << 6));
    v2f accA = mkv2(wts[OFF_B2 + o], 0.f);
    v2f accB = mkv2(0.f, 0.f);
#pragma unroll
    for (int q = 0; q < 16; q += 2) {
      float4 wa = w4[q];
      accA = vfma2(mkv2(wa.x, wa.y), h1v[2 * q], accA);
      accB = vfma2(mkv2(wa.z, wa.w), h1v[2 * q + 1], accB);
      float4 wb = w4[q + 1];
      accA = vfma2(mkv2(wb.x, wb.y), h1v[2 * q + 2], accA);
      accB = vfma2(mkv2(wb.z, wb.w), h1v[2 * q + 3], accB);
    }
    float s = (accA.x + accA.y) + (accB.x + accB.y);
    mx = fmaxf(mx, s);
  }
  mx = fmaxf(mx, 0.f);  // relu commutes with channel-max

  // softmax over 32 kk lanes + weighted sum of neighbor coords
  float gm = mx;
#pragma unroll
  for (int off = 16; off > 0; off >>= 1) gm = fmaxf(gm, __shfl_xor(gm, off));
  float e = __expf(mx - gm);
  float es = e, ex = e * rv.x, ey = e * rv.y, ez = e * rv.z;
#pragma unroll
  for (int off = 16; off > 0; off >>= 1) {
    es += __shfl_xor(es, off);
    ex += __shfl_xor(ex, off);
    ey += __shfl_xor(ey, off);
    ez += __shfl_xor(ez, off);
  }
  if (kk == 0) {
    float inv = 1.f / es;
    out[(b * 3 + 0) * NN + n] = ex * inv;
    out[(b * 3 + 1) * NN + n] = ey * inv;
    out[(b * 3 + 2) * NN + n] = ez * inv;
  }
}

extern "C" void kernel_launch(void* const* d_in, const int* in_sizes, int n_in,
                              void* d_out, int out_size, void* d_ws, size_t ws_size,
                              hipStream_t stream) {
  const float* p1 = (const float*)d_in[0];
  const float* p2 = (const float*)d_in[1];
  float* ws = (float*)d_ws;
  float* out = (float*)d_out;

  prep_kernel<<<128, 256, 0, stream>>>(
      p1, p2,
      (const float*)d_in[3],  (const float*)d_in[4],  (const float*)d_in[5],
      (const float*)d_in[6],  (const float*)d_in[7],  (const float*)d_in[8],
      (const float*)d_in[9],  (const float*)d_in[10], (const float*)d_in[11],
      (const float*)d_in[12], (const float*)d_in[13], (const float*)d_in[14],
      (const float*)d_in[15], (const float*)d_in[16], (const float*)d_in[17],
      (const float*)d_in[18], (const float*)d_in[19], (const float*)d_in[20],
      ws);
  knn_kernel<<<512, 256, 0, stream>>>(p1, (const float4*)(ws + OFF_PACK),
                                      (int*)(ws + OFF_IDX));
  fusion_kernel<<<2048, 256, 0, stream>>>(p1, ws, (const float4*)(ws + OFF_PACK),
                                          (const int*)(ws + OFF_IDX), out);
}